// Round 12
// baseline (42.427 us; speedup 1.0000x reference)
//
#include <hip/hip_runtime.h>

#define Cc 8
#define Hh 128
#define Ww 128
#define Nn 64
#define Bb 8
#define Dd 169            // (C+2)*C + C + C*C + C + C + 1
#define HW (Hh * Ww)
#define GN 8              // n's per block (seg re-read cut from 64x to 8x)
#define NGRP (Nn / GN)    // 8 n-groups
#define CHUNKS 16         // px chunks per (b, n-group)
#define NBLK (Bb * NGRP * CHUNKS)  // 1024 blocks
#define PXB (HW / CHUNKS)          // 1024 px per block; 4 px per thread
#define WSTRIDE 88                 // u32 per bn in packed table (85 used)
#define RED_OFF (Bb * Nn * WSTRIDE)   // float offset of reduction slots in ws
#define SLOTS (NGRP * CHUNKS)         // 128 partial-slots per batch b

#define INV128 (1.0f / 128.0f)

typedef __fp16 f16x2 __attribute__((ext_vector_type(2)));

static __device__ __forceinline__ f16x2 pk(float a, float b) {
    return __builtin_amdgcn_cvt_pkrtz(a, b);   // v_cvt_pkrtz_f16_f32
}
static __device__ __forceinline__ uint32_t pku(float a, float b) {
    f16x2 t = pk(a, b); uint32_t u; __builtin_memcpy(&u, &t, 4); return u;
}
static __device__ __forceinline__ f16x2 u2h(uint32_t u) {
    f16x2 r; __builtin_memcpy(&r, &u, 4); return r;
}
static __device__ __forceinline__ f16x2 max2(f16x2 a, f16x2 b) {
    return __builtin_elementwise_max(a, b);    // v_pk_max_f16
}

// ---- full-rate pk_fma, SGPR weight-pair broadcast via op_sel (validated r11) ----
static __device__ __forceinline__ void fma_lo(f16x2& acc, uint32_t w, f16x2 f) {
    asm("v_pk_fma_f16 %0, %1, %2, %0 op_sel:[0,0,0] op_sel_hi:[0,1,1]"
        : "+v"(acc) : "s"(w), "v"(f));
}
static __device__ __forceinline__ void fma_hi(f16x2& acc, uint32_t w, f16x2 f) {
    asm("v_pk_fma_f16 %0, %1, %2, %0 op_sel:[1,0,0] op_sel_hi:[1,1,1]"
        : "+v"(acc) : "s"(w), "v"(f));
}
static __device__ __forceinline__ f16x2 fma_lo4(uint32_t w, f16x2 f, f16x2 c) {
    f16x2 o;
    asm("v_pk_fma_f16 %0, %1, %2, %3 op_sel:[0,0,0] op_sel_hi:[0,1,1]"
        : "=v"(o) : "s"(w), "v"(f), "v"(c));
    return o;
}
static __device__ __forceinline__ f16x2 fma_hi4(uint32_t w, f16x2 f, f16x2 c) {
    f16x2 o;
    asm("v_pk_fma_f16 %0, %1, %2, %3 op_sel:[1,0,0] op_sel_hi:[1,1,1]"
        : "=v"(o) : "s"(w), "v"(f), "v"(c));
    return o;
}

// ---- kernel A: gather + f16-pack per-bn weight vectors (scatter paid once) ----
// pair layout (u32): [0..39]=w1 rows (5/row: (c0,c1)..(c6,c7),(w8,w9)),
// [40..71]=w2 rows (4/row), [72..75]=w3, [76..79]=b1, [80..83]=b2, [84]=(b3,0)
__global__ void pack_weights(const float* __restrict__ conv_weight,
                             const int*   __restrict__ ind,
                             uint32_t*    __restrict__ wt) {
    const int bn = blockIdx.x;       // 512
    const int j  = threadIdx.x;      // 96 threads
    const int b  = bn >> 6;
    const int ind_bn = ind[bn];
    const float* src = conv_weight + (size_t)b * Dd * HW + ind_bn;
    if (j < 85) {
        int d0, d1;
        if (j < 40)      { d0 = (j / 5) * 10 + (j % 5) * 2; d1 = d0 + 1; }
        else if (j < 72) { d0 = 88  + 2 * (j - 40); d1 = d0 + 1; }
        else if (j < 76) { d0 = 160 + 2 * (j - 72); d1 = d0 + 1; }
        else if (j < 80) { d0 = 80  + 2 * (j - 76); d1 = d0 + 1; }
        else if (j < 84) { d0 = 152 + 2 * (j - 80); d1 = d0 + 1; }
        else             { d0 = 168; d1 = -1; }
        const float a = src[(size_t)d0 * HW];
        const float c = (d1 >= 0) ? src[(size_t)d1 * HW] : 0.f;
        wt[bn * WSTRIDE + j] = pku(a, c);
    }
}

// ---- kernel B: seg tile in regs ONCE, loop over 8 n's ----
__global__ __launch_bounds__(256)
void seg_dice_main(const float* __restrict__ seg_feat,
                   const float* __restrict__ mask,
                   const int*   __restrict__ ind,
                   const float* __restrict__ target,
                   const uint32_t* __restrict__ wtab,
                   float* __restrict__ red_base) {
    const int bid   = blockIdx.x;
    const int b     = bid & 7;          // same-b blocks share an XCD (round-robin)
    const int t     = bid >> 3;         // 0..127 = ngrp*CHUNKS + chunk
    const int ngrp  = t >> 4;
    const int chunk = t & (CHUNKS - 1);
    const int tid   = threadIdx.x;

    const int p = chunk * PXB + (tid << 2);     // 4 consecutive px, same row

    // ---- seg px-tile -> registers, once per block ----
    const float* seg_b = seg_feat + (size_t)b * Cc * HW;
    f16x2 sA[8], sB[8];
    #pragma unroll
    for (int c = 0; c < 8; ++c) {
        const float4 v = *(const float4*)(seg_b + c * HW + p);
        sA[c] = pk(v.x, v.y);
        sB[c] = pk(v.z, v.w);
    }
    // block-constant px coords / 128 (exact in f16)
    const float xf = (float)(p & (Ww - 1)) * INV128;
    const float yf = (float)(p >> 7) * INV128;
    const f16x2 xq01 = pk(xf, xf + INV128);
    const f16x2 xq23 = pk(xf + 2.f * INV128, xf + 3.f * INV128);
    const f16x2 yq   = pk(yf, yf);

    const int bnb = __builtin_amdgcn_readfirstlane(b * Nn + ngrp * GN);

    float inter = 0.f, ps = 0.f, ts = 0.f;

    #pragma unroll 1
    for (int n = 0; n < GN; ++n) {
        const int bn = bnb + n;

        // target row chunk (issued early; consumed at the end of the body)
        const float4 t4 = *(const float4*)(target + (size_t)bn * HW + p);

        // uniform weight table -> SGPRs
        uint32_t wq[88];
        {
            const uint4* wt4 = (const uint4*)(wtab + bn * WSTRIDE);
            #pragma unroll
            for (int k = 0; k < 22; ++k) {
                const uint4 q = wt4[k];
                wq[4 * k + 0] = q.x; wq[4 * k + 1] = q.y;
                wq[4 * k + 2] = q.z; wq[4 * k + 3] = q.w;
            }
        }
        const float m  = mask[bn];
        const int   ib = ind[bn];

        // per-n spatial offsets (exact f16 subtraction of k/128 values)
        const float x0 = (float)(ib & (Ww - 1)) * INV128;
        const float y0 = (float)(ib >> 7) * INV128;
        const f16x2 x0s = pk(x0, x0);
        const f16x2 y0s = pk(y0, y0);
        const f16x2 xr01 = xq01 - x0s;
        const f16x2 xr23 = xq23 - x0s;
        const f16x2 yr2  = yq   - y0s;

        // bias splats -> VGPRs (per n)
        f16x2 b1v[8], b2v[8];
        #pragma unroll
        for (int k = 0; k < 4; ++k) {
            const f16x2 p1 = u2h(wq[76 + k]);
            b1v[2 * k]     = f16x2{p1.x, p1.x};
            b1v[2 * k + 1] = f16x2{p1.y, p1.y};
            const f16x2 p2 = u2h(wq[80 + k]);
            b2v[2 * k]     = f16x2{p2.x, p2.x};
            b2v[2 * k + 1] = f16x2{p2.y, p2.y};
        }
        const f16x2 pb3 = u2h(wq[84]);
        const f16x2 b3v = f16x2{pb3.x, pb3.x};

        // ---- layer 1: 10 -> 8, relu ----
        f16x2 h1A[8], h1B[8];
        #pragma unroll
        for (int o = 0; o < 8; ++o) {
            const uint32_t wxy = wq[5 * o + 4];            // (w8, w9)
            const f16x2 base = fma_hi4(wxy, yr2, b1v[o]);  // w9*yr + b1
            f16x2 a01 = fma_lo4(wxy, xr01, base);          // + w8*xr
            f16x2 a23 = fma_lo4(wxy, xr23, base);
            #pragma unroll
            for (int k = 0; k < 4; ++k) {
                const uint32_t w = wq[5 * o + k];          // (c2k, c2k+1)
                fma_lo(a01, w, sA[2 * k]);  fma_hi(a01, w, sA[2 * k + 1]);
                fma_lo(a23, w, sB[2 * k]);  fma_hi(a23, w, sB[2 * k + 1]);
            }
            const f16x2 z = {(__fp16)0.f, (__fp16)0.f};
            h1A[o] = max2(a01, z);
            h1B[o] = max2(a23, z);
        }

        // ---- layer 2: 8 -> 8, relu ----
        f16x2 h2A[8], h2B[8];
        #pragma unroll
        for (int o = 0; o < 8; ++o) {
            const uint32_t w0 = wq[40 + 4 * o];
            f16x2 a01 = fma_lo4(w0, h1A[0], b2v[o]);
            f16x2 a23 = fma_lo4(w0, h1B[0], b2v[o]);
            fma_hi(a01, w0, h1A[1]);  fma_hi(a23, w0, h1B[1]);
            #pragma unroll
            for (int k = 1; k < 4; ++k) {
                const uint32_t w = wq[40 + 4 * o + k];
                fma_lo(a01, w, h1A[2 * k]);  fma_hi(a01, w, h1A[2 * k + 1]);
                fma_lo(a23, w, h1B[2 * k]);  fma_hi(a23, w, h1B[2 * k + 1]);
            }
            const f16x2 z = {(__fp16)0.f, (__fp16)0.f};
            h2A[o] = max2(a01, z);
            h2B[o] = max2(a23, z);
        }

        // ---- layer 3: 8 -> 1, sigmoid + dice (f32) ----
        f16x2 z01 = fma_lo4(wq[72], h2A[0], b3v);
        f16x2 z23 = fma_lo4(wq[72], h2B[0], b3v);
        fma_hi(z01, wq[72], h2A[1]);  fma_hi(z23, wq[72], h2B[1]);
        #pragma unroll
        for (int k = 1; k < 4; ++k) {
            const uint32_t w = wq[72 + k];
            fma_lo(z01, w, h2A[2 * k]);  fma_hi(z01, w, h2A[2 * k + 1]);
            fma_lo(z23, w, h2B[2 * k]);  fma_hi(z23, w, h2B[2 * k + 1]);
        }

        const float o0 = __builtin_amdgcn_rcpf(1.f + __expf(-(float)z01.x));
        const float o1 = __builtin_amdgcn_rcpf(1.f + __expf(-(float)z01.y));
        const float o2 = __builtin_amdgcn_rcpf(1.f + __expf(-(float)z23.x));
        const float o3 = __builtin_amdgcn_rcpf(1.f + __expf(-(float)z23.y));

        float in_ = 0.f, ps_ = 0.f, ts_ = 0.f;
        in_ = fmaf(o0, t4.x, in_); in_ = fmaf(o1, t4.y, in_);
        in_ = fmaf(o2, t4.z, in_); in_ = fmaf(o3, t4.w, in_);
        ps_ = fmaf(o0, o0, ps_); ps_ = fmaf(o1, o1, ps_);
        ps_ = fmaf(o2, o2, ps_); ps_ = fmaf(o3, o3, ps_);
        ts_ = fmaf(t4.x, t4.x, ts_); ts_ = fmaf(t4.y, t4.y, ts_);
        ts_ = fmaf(t4.z, t4.z, ts_); ts_ = fmaf(t4.w, t4.w, ts_);

        const float m2 = m * m;
        inter = fmaf(m2, in_, inter);
        ps    = fmaf(m2, ps_, ps);
        ts    = fmaf(m2, ts_, ts);
    }

    // wave reduce then cross-wave via LDS
    #pragma unroll
    for (int off = 32; off > 0; off >>= 1) {
        inter += __shfl_down(inter, off);
        ps    += __shfl_down(ps,    off);
        ts    += __shfl_down(ts,    off);
    }
    __shared__ float red[3][4];
    const int wave = tid >> 6;
    if ((tid & 63) == 0) { red[0][wave] = inter; red[1][wave] = ps; red[2][wave] = ts; }
    __syncthreads();
    if (tid == 0) {
        red_base[(b * 3 + 0) * SLOTS + t] = red[0][0] + red[0][1] + red[0][2] + red[0][3];
        red_base[(b * 3 + 1) * SLOTS + t] = red[1][0] + red[1][1] + red[1][2] + red[1][3];
        red_base[(b * 3 + 2) * SLOTS + t] = red[2][0] + red[2][1] + red[2][2] + red[2][3];
    }
}

// deterministic epilogue: 24 series (8 b x 3 comps) x 128 partials
__global__ void seg_dice_final(const float* __restrict__ red_base, float* __restrict__ out) {
    __shared__ float red[24][4];
    const int tid = threadIdx.x;  // 128 threads
    if (tid < 96) {
        const int series = tid >> 2;   // 0..23
        const int part   = tid & 3;    // 0..3
        const float4* p = (const float4*)(red_base + series * SLOTS + part * 32);
        float s = 0.f;
        #pragma unroll
        for (int i = 0; i < 8; ++i) { const float4 v = p[i]; s += (v.x + v.y) + (v.z + v.w); }
        red[series][part] = s;
    }
    __syncthreads();
    if (tid == 0) {
        float acc = 0.f;
        #pragma unroll
        for (int b = 0; b < Bb; ++b) {
            const float inter = red[b*3+0][0] + red[b*3+0][1] + red[b*3+0][2] + red[b*3+0][3];
            const float p2    = red[b*3+1][0] + red[b*3+1][1] + red[b*3+1][2] + red[b*3+1][3];
            const float t2    = red[b*3+2][0] + red[b*3+2][1] + red[b*3+2][2] + red[b*3+2][3];
            acc += 1.0f - (2.0f * inter + 1.0f) / (p2 + t2 + 1.0f);
        }
        out[0] = acc * (1.0f / (float)Bb);
    }
}

extern "C" void kernel_launch(void* const* d_in, const int* in_sizes, int n_in,
                              void* d_out, int out_size, void* d_ws, size_t ws_size,
                              hipStream_t stream) {
    const float* seg_feat    = (const float*)d_in[0];
    const float* conv_weight = (const float*)d_in[1];
    const float* mask        = (const float*)d_in[2];
    const int*   ind         = (const int*)d_in[3];
    const float* target      = (const float*)d_in[4];
    float* out = (float*)d_out;
    float* ws  = (float*)d_ws;

    uint32_t* wtab     = (uint32_t*)ws;
    float*    red_base = ws + RED_OFF;

    pack_weights<<<Bb * Nn, 96, 0, stream>>>(conv_weight, ind, wtab);
    seg_dice_main<<<NBLK, 256, 0, stream>>>(seg_feat, mask, ind, target, wtab, red_base);
    seg_dice_final<<<1, 128, 0, stream>>>(red_base, out);
}